// Round 4
// baseline (225.216 us; speedup 1.0000x reference)
//
#include <hip/hip_runtime.h>
#include <hip/hip_fp16.h>

#define NPTS   65536
#define KNN    8
#define CDIM   64
#define SHB    9
#define NCODES 8192
#define RECW   5   // __half2 (dwords) per lane per code record
#define NPHASE 4
#define PSHIFT 11  // 2048 codes/slice -> 2.6 MB record slice, fits 4 MB per-XCD L2
#define PTSW   16  // points per wave
#define NBLK   (NPTS / (PTSW * 4))   // 1024 blocks = 4 blocks/CU, co-resident

// Record layout: rec[code][j*64 + lane], j=0..4, each a __half2:
//   j=0:(s0,s1) j=1:(s2,s3) j=2:(s4,s5) j=3:(s6,s7) j=4:(s8, codes[code][lane])

__global__ __launch_bounds__(256) void repack_kernel(
    const float* __restrict__ codes,   // (8192,64)
    const float* __restrict__ shc,     // (8192,576)
    __half2* __restrict__ rec)         // (8192, 5*64)
{
    const int wid  = threadIdx.x >> 6;
    const int lane = threadIdx.x & 63;
    const int c    = blockIdx.x * 4 + wid;   // one wave per code

    const float* p = shc + (size_t)c * (CDIM * SHB) + lane * SHB;
    float v[SHB];
#pragma unroll
    for (int s = 0; s < SHB; ++s) v[s] = p[s];
    const float cv = codes[c * CDIM + lane];

    __half2* r = rec + (size_t)c * (RECW * 64) + lane;
    r[0 * 64] = __floats2half2_rn(v[0], v[1]);
    r[1 * 64] = __floats2half2_rn(v[2], v[3]);
    r[2 * 64] = __floats2half2_rn(v[4], v[5]);
    r[3 * 64] = __floats2half2_rn(v[6], v[7]);
    r[4 * 64] = __floats2half2_rn(v[8], cv);
}

// Persistent phased gather kernel, spill-proofed:
//  - amdgpu_waves_per_eu(4,4) pins the allocator to the 128-VGPR budget
//    (launch_bounds(256,4) alone let it target 8 waves/EU -> 64 VGPR -> spill).
//  - accumulators statically indexed (full unroll) so they live in VGPRs.
//  - output stores are non-temporal so 33.5 MB of streams don't evict the
//    L2-resident code slice.
__global__ __launch_bounds__(256)
__attribute__((amdgpu_waves_per_eu(4, 4)))
void shcode_phased(
    const float* __restrict__ qp,
    const float* __restrict__ vd,
    const float* __restrict__ cpos,
    const __half2* __restrict__ rec,
    const int*   __restrict__ knn,
    float* __restrict__ out)
{
    const int lane = threadIdx.x & 63;
    const int wid  = __builtin_amdgcn_readfirstlane((int)(threadIdx.x >> 6));
    const int p0   = (blockIdx.x * 4 + wid) * PTSW;   // wave-uniform base point

    float acc_c[PTSW], acc_s[PTSW], wsum[PTSW];
#pragma unroll
    for (int p = 0; p < PTSW; ++p) { acc_c[p] = 0.f; acc_s[p] = 0.f; wsum[p] = 0.f; }

    for (int ph = 0; ph < NPHASE; ++ph) {
#pragma unroll
        for (int p = 0; p < PTSW; ++p) {   // fully unrolled -> static acc indexing
            const int n = p0 + p;          // wave-uniform -> scalar loads below

            int ids[KNN];
#pragma unroll
            for (int k = 0; k < KNN; ++k) ids[k] = knn[n * KNN + k];

            int any = 0;
#pragma unroll
            for (int k = 0; k < KNN; ++k) any |= ((ids[k] >> PSHIFT) == ph) ? 1 : 0;
            if (!any) continue;            // wave-uniform branch

            const float qx = qp[n * 3 + 0];
            const float qy = qp[n * 3 + 1];
            const float qz = qp[n * 3 + 2];
            const float x  = vd[n * 3 + 0];
            const float y  = vd[n * 3 + 1];
            const float z  = vd[n * 3 + 2];
            const float xx = x * x, yy = y * y, zz = z * z;
            const float sm0 = 0.28209479177387814f;
            const float sm1 = -0.4886025119029199f * y;
            const float sm2 =  0.4886025119029199f * z;
            const float sm3 = -0.4886025119029199f * x;
            const float sm4 =  1.0925484305920792f * (x * y);
            const float sm5 = -1.0925484305920792f * (y * z);
            const float sm6 =  0.31539156525252005f * (2.0f * zz - xx - yy);
            const float sm7 = -1.0925484305920792f * (x * z);
            const float sm8 =  0.5462742152960396f * (xx - yy);

#pragma unroll
            for (int k = 0; k < KNN; ++k) {
                const int id = ids[k];
                if ((id >> PSHIFT) != ph) continue;   // wave-uniform

                const float dx = qx - cpos[id * 3 + 0];
                const float dy = qy - cpos[id * 3 + 1];
                const float dz = qz - cpos[id * 3 + 2];
                const float w  = 1.0f / (dx * dx + dy * dy + dz * dz + 1e-16f);

                const __half2* r = rec + (size_t)id * (RECW * 64) + lane;
                const float2 f0 = __half22float2(r[0 * 64]);
                const float2 f1 = __half22float2(r[1 * 64]);
                const float2 f2 = __half22float2(r[2 * 64]);
                const float2 f3 = __half22float2(r[3 * 64]);
                const float2 f4 = __half22float2(r[4 * 64]);

                const float agg = sm0 * f0.x + sm1 * f0.y + sm2 * f1.x
                                + sm3 * f1.y + sm4 * f2.x + sm5 * f2.y
                                + sm6 * f3.x + sm7 * f3.y + sm8 * f4.x;
                acc_s[p] += w * agg;
                acc_c[p] += w * f4.y;
                wsum[p]  += w;
            }
        }
        __syncthreads();   // keep block's waves phase-aligned
    }

#pragma unroll
    for (int p = 0; p < PTSW; ++p) {
        const int n = p0 + p;
        const float inv = 1.0f / wsum[p];
        __builtin_nontemporal_store(acc_c[p] * inv, &out[n * CDIM + lane]);
        __builtin_nontemporal_store(acc_s[p] * inv,
                                    &out[(size_t)NPTS * CDIM + n * CDIM + lane]);
    }
}

// --- fallback (round-1 fp32 direct-gather) if workspace too small ---
__global__ __launch_bounds__(256) void shcode_kernel(
    const float* __restrict__ qp, const float* __restrict__ vd,
    const float* __restrict__ cpos, const float* __restrict__ codes,
    const float* __restrict__ shc, const int* __restrict__ knn,
    float* __restrict__ out)
{
    const int wid  = threadIdx.x >> 6;
    const int lane = threadIdx.x & 63;
    const int n    = blockIdx.x * 4 + wid;

    const float x = vd[n * 3 + 0], y = vd[n * 3 + 1], z = vd[n * 3 + 2];
    const float xx = x * x, yy = y * y, zz = z * z;
    const float sm0 = 0.28209479177387814f;
    const float sm1 = -0.4886025119029199f * y;
    const float sm2 =  0.4886025119029199f * z;
    const float sm3 = -0.4886025119029199f * x;
    const float sm4 =  1.0925484305920792f * (x * y);
    const float sm5 = -1.0925484305920792f * (y * z);
    const float sm6 =  0.31539156525252005f * (2.0f * zz - xx - yy);
    const float sm7 = -1.0925484305920792f * (x * z);
    const float sm8 =  0.5462742152960396f * (xx - yy);

    const float qx = qp[n * 3 + 0], qy = qp[n * 3 + 1], qz = qp[n * 3 + 2];

    int idx[KNN]; float w[KNN]; float wsum = 0.0f;
#pragma unroll
    for (int k = 0; k < KNN; ++k) {
        int id = __builtin_amdgcn_readfirstlane(knn[n * KNN + k]);
        idx[k] = id;
        const float dx = qx - cpos[id * 3 + 0];
        const float dy = qy - cpos[id * 3 + 1];
        const float dz = qz - cpos[id * 3 + 2];
        const float sd = dx * dx + dy * dy + dz * dz + 1e-16f;
        w[k] = 1.0f / sd; wsum += w[k];
    }
    const float winv = 1.0f / wsum;

    float acc_c = 0.0f, acc_s = 0.0f;
#pragma unroll
    for (int k = 0; k < KNN; ++k) {
        const float wk = w[k] * winv;
        acc_c += wk * codes[(size_t)idx[k] * CDIM + lane];
        const float* p = shc + (size_t)idx[k] * (CDIM * SHB) + lane * SHB;
        acc_s += wk * (sm0 * p[0] + sm1 * p[1] + sm2 * p[2]
                     + sm3 * p[3] + sm4 * p[4] + sm5 * p[5]
                     + sm6 * p[6] + sm7 * p[7] + sm8 * p[8]);
    }
    out[n * CDIM + lane] = acc_c;
    out[(size_t)NPTS * CDIM + n * CDIM + lane] = acc_s;
}

extern "C" void kernel_launch(void* const* d_in, const int* in_sizes, int n_in,
                              void* d_out, int out_size, void* d_ws, size_t ws_size,
                              hipStream_t stream) {
    const float* qp    = (const float*)d_in[0];
    const float* vd    = (const float*)d_in[1];
    const float* cpos  = (const float*)d_in[2];
    const float* codes = (const float*)d_in[3];
    const float* shc   = (const float*)d_in[4];
    const int*   knn   = (const int*)d_in[6];
    float* out = (float*)d_out;

    const size_t rec_bytes = (size_t)NCODES * RECW * 64 * sizeof(__half2); // 10.5 MB

    if (ws_size >= rec_bytes) {
        __half2* rec = (__half2*)d_ws;
        hipLaunchKernelGGL(repack_kernel, dim3(NCODES / 4), dim3(256), 0, stream,
                           codes, shc, rec);
        hipLaunchKernelGGL(shcode_phased, dim3(NBLK), dim3(256), 0, stream,
                           qp, vd, cpos, rec, knn, out);
    } else {
        hipLaunchKernelGGL(shcode_kernel, dim3(NPTS / 4), dim3(256), 0, stream,
                           qp, vd, cpos, codes, shc, knn, out);
    }
}

// Round 5
// 74.092 us; speedup vs baseline: 3.0397x; 3.0397x over previous
//
#include <hip/hip_runtime.h>
#include <hip/hip_fp16.h>

#define NPTS   65536
#define KNN    8
#define CDIM   64
#define SHB    9
#define NCODES 8192
#define RECW   5   // __half2 (dwords) per lane per code record
#define NPHASE 4
#define PSHIFT 11  // 2048 codes/slice -> 2.6 MB record slice fits 4 MB per-XCD L2
#define PTSW   16  // points per wave
#define WAVES  4
#define NBLK   (NPTS / (PTSW * WAVES))   // 1024 blocks, co-resident
#define LSTRIDE 96 // LDS bytes per point: ids u16[8]@0, wbar f32[8]@16, sm f32[9]@48, mask u32@84

// Record layout: rec[code][j*64 + lane], j=0..4, each a __half2:
//   j=0:(s0,s1) j=1:(s2,s3) j=2:(s4,s5) j=3:(s6,s7) j=4:(s8, codes[code][lane])

__global__ __launch_bounds__(256) void repack_kernel(
    const float* __restrict__ codes,   // (8192,64)
    const float* __restrict__ shc,     // (8192,576)
    __half2* __restrict__ rec)         // (8192, 5*64)
{
    const int wid  = threadIdx.x >> 6;
    const int lane = threadIdx.x & 63;
    const int c    = blockIdx.x * 4 + wid;

    const float* p = shc + (size_t)c * (CDIM * SHB) + lane * SHB;
    float v[SHB];
#pragma unroll
    for (int s = 0; s < SHB; ++s) v[s] = p[s];
    const float cv = codes[c * CDIM + lane];

    __half2* r = rec + (size_t)c * (RECW * 64) + lane;
    r[0 * 64] = __floats2half2_rn(v[0], v[1]);
    r[1 * 64] = __floats2half2_rn(v[2], v[3]);
    r[2 * 64] = __floats2half2_rn(v[4], v[5]);
    r[3 * 64] = __floats2half2_rn(v[6], v[7]);
    r[4 * 64] = __floats2half2_rn(v[8], cv);
}

// Phased persistent kernel, spill-proof variant:
//   per-point state (ids, normalized weights, sm basis, phase mask) lives in
//   LDS; registers hold only acc_c[16], acc_s[16] (static index via tiny
//   unrolled body). Phase ph touches only codes in [ph*2048,(ph+1)*2048).
__global__ __launch_bounds__(256) void shcode_phased2(
    const float* __restrict__ qp,
    const float* __restrict__ vd,
    const float* __restrict__ cpos,
    const __half2* __restrict__ rec,
    const int*   __restrict__ knn,
    float* __restrict__ out)
{
    __shared__ unsigned char lds[WAVES * PTSW * LSTRIDE];   // 6 KB

    const int tid   = threadIdx.x;
    const int lane  = tid & 63;
    const int wid   = tid >> 6;
    const int pbase = (blockIdx.x * WAVES + wid) * PTSW;

    // ---- precompute: lane l (< PTSW) owns point pbase+l ----
    if (lane < PTSW) {
        const int n = pbase + lane;
        unsigned char* pr = lds + (wid * PTSW + lane) * LSTRIDE;
        unsigned short* ids16 = (unsigned short*)(pr + 0);
        float*          wbar  = (float*)(pr + 16);
        float*          smv   = (float*)(pr + 48);
        unsigned int*   maskp = (unsigned int*)(pr + 84);

        const float qx = qp[n * 3 + 0];
        const float qy = qp[n * 3 + 1];
        const float qz = qp[n * 3 + 2];

        int   ids[KNN];
        float w[KNN];
        float wsum = 0.0f;
#pragma unroll
        for (int k = 0; k < KNN; ++k) {
            const int id = knn[n * KNN + k];
            ids[k] = id;
            const float dx = qx - cpos[id * 3 + 0];
            const float dy = qy - cpos[id * 3 + 1];
            const float dz = qz - cpos[id * 3 + 2];
            w[k] = 1.0f / (dx * dx + dy * dy + dz * dz + 1e-16f);
            wsum += w[k];
        }
        const float inv = 1.0f / wsum;
        unsigned int mask = 0u;
#pragma unroll
        for (int k = 0; k < KNN; ++k) {
            ids16[k] = (unsigned short)ids[k];
            wbar[k]  = w[k] * inv;
            mask |= 1u << (((unsigned)ids[k] >> PSHIFT) * 8 + k);
        }
        *maskp = mask;

        const float x = vd[n * 3 + 0];
        const float y = vd[n * 3 + 1];
        const float z = vd[n * 3 + 2];
        const float xx = x * x, yy = y * y, zz = z * z;
        smv[0] = 0.28209479177387814f;
        smv[1] = -0.4886025119029199f * y;
        smv[2] =  0.4886025119029199f * z;
        smv[3] = -0.4886025119029199f * x;
        smv[4] =  1.0925484305920792f * (x * y);
        smv[5] = -1.0925484305920792f * (y * z);
        smv[6] =  0.31539156525252005f * (2.0f * zz - xx - yy);
        smv[7] = -1.0925484305920792f * (x * z);
        smv[8] =  0.5462742152960396f * (xx - yy);
    }
    __syncthreads();

    float acc_c[PTSW], acc_s[PTSW];
#pragma unroll
    for (int p = 0; p < PTSW; ++p) { acc_c[p] = 0.0f; acc_s[p] = 0.0f; }

    for (int ph = 0; ph < NPHASE; ++ph) {
#pragma unroll
        for (int p = 0; p < PTSW; ++p) {
            const unsigned char* pr = lds + (wid * PTSW + p) * LSTRIDE;
            const unsigned int mask =
                (unsigned int)__builtin_amdgcn_readfirstlane(
                    (int)*(const unsigned int*)(pr + 84));
            unsigned int m8 = (mask >> (8 * ph)) & 0xffu;
            if (!m8) continue;                      // uniform scalar branch

            const float* smv = (const float*)(pr + 48);
            const float s0 = smv[0], s1 = smv[1], s2 = smv[2];
            const float s3 = smv[3], s4 = smv[4], s5 = smv[5];
            const float s6 = smv[6], s7 = smv[7], s8 = smv[8];

            while (m8) {
                const int k = __builtin_ctz(m8);
                m8 &= m8 - 1u;
                const int id = __builtin_amdgcn_readfirstlane(
                    (int)((const unsigned short*)pr)[k]);
                const float wk = ((const float*)(pr + 16))[k];

                const __half2* r = rec + (size_t)id * (RECW * 64) + lane;
                const float2 f0 = __half22float2(r[0 * 64]);
                const float2 f1 = __half22float2(r[1 * 64]);
                const float2 f2 = __half22float2(r[2 * 64]);
                const float2 f3 = __half22float2(r[3 * 64]);
                const float2 f4 = __half22float2(r[4 * 64]);

                const float agg = s0 * f0.x + s1 * f0.y + s2 * f1.x
                                + s3 * f1.y + s4 * f2.x + s5 * f2.y
                                + s6 * f3.x + s7 * f3.y + s8 * f4.x;
                acc_s[p] += wk * agg;
                acc_c[p] += wk * f4.y;
            }
        }
        __syncthreads();   // keep block's waves phase-aligned
    }

#pragma unroll
    for (int p = 0; p < PTSW; ++p) {
        const int n = pbase + p;
        __builtin_nontemporal_store(acc_c[p], &out[n * CDIM + lane]);
        __builtin_nontemporal_store(acc_s[p],
                                    &out[(size_t)NPTS * CDIM + n * CDIM + lane]);
    }
}

// --- fallback (round-1 fp32 direct-gather) if workspace too small ---
__global__ __launch_bounds__(256) void shcode_kernel(
    const float* __restrict__ qp, const float* __restrict__ vd,
    const float* __restrict__ cpos, const float* __restrict__ codes,
    const float* __restrict__ shc, const int* __restrict__ knn,
    float* __restrict__ out)
{
    const int wid  = threadIdx.x >> 6;
    const int lane = threadIdx.x & 63;
    const int n    = blockIdx.x * 4 + wid;

    const float x = vd[n * 3 + 0], y = vd[n * 3 + 1], z = vd[n * 3 + 2];
    const float xx = x * x, yy = y * y, zz = z * z;
    const float sm0 = 0.28209479177387814f;
    const float sm1 = -0.4886025119029199f * y;
    const float sm2 =  0.4886025119029199f * z;
    const float sm3 = -0.4886025119029199f * x;
    const float sm4 =  1.0925484305920792f * (x * y);
    const float sm5 = -1.0925484305920792f * (y * z);
    const float sm6 =  0.31539156525252005f * (2.0f * zz - xx - yy);
    const float sm7 = -1.0925484305920792f * (x * z);
    const float sm8 =  0.5462742152960396f * (xx - yy);

    const float qx = qp[n * 3 + 0], qy = qp[n * 3 + 1], qz = qp[n * 3 + 2];

    int idx[KNN]; float w[KNN]; float wsum = 0.0f;
#pragma unroll
    for (int k = 0; k < KNN; ++k) {
        int id = __builtin_amdgcn_readfirstlane(knn[n * KNN + k]);
        idx[k] = id;
        const float dx = qx - cpos[id * 3 + 0];
        const float dy = qy - cpos[id * 3 + 1];
        const float dz = qz - cpos[id * 3 + 2];
        const float sd = dx * dx + dy * dy + dz * dz + 1e-16f;
        w[k] = 1.0f / sd; wsum += w[k];
    }
    const float winv = 1.0f / wsum;

    float acc_c = 0.0f, acc_s = 0.0f;
#pragma unroll
    for (int k = 0; k < KNN; ++k) {
        const float wk = w[k] * winv;
        acc_c += wk * codes[(size_t)idx[k] * CDIM + lane];
        const float* p = shc + (size_t)idx[k] * (CDIM * SHB) + lane * SHB;
        acc_s += wk * (sm0 * p[0] + sm1 * p[1] + sm2 * p[2]
                     + sm3 * p[3] + sm4 * p[4] + sm5 * p[5]
                     + sm6 * p[6] + sm7 * p[7] + sm8 * p[8]);
    }
    out[n * CDIM + lane] = acc_c;
    out[(size_t)NPTS * CDIM + n * CDIM + lane] = acc_s;
}

extern "C" void kernel_launch(void* const* d_in, const int* in_sizes, int n_in,
                              void* d_out, int out_size, void* d_ws, size_t ws_size,
                              hipStream_t stream) {
    const float* qp    = (const float*)d_in[0];
    const float* vd    = (const float*)d_in[1];
    const float* cpos  = (const float*)d_in[2];
    const float* codes = (const float*)d_in[3];
    const float* shc   = (const float*)d_in[4];
    const int*   knn   = (const int*)d_in[6];
    float* out = (float*)d_out;

    const size_t rec_bytes = (size_t)NCODES * RECW * 64 * sizeof(__half2); // 10.5 MB

    if (ws_size >= rec_bytes) {
        __half2* rec = (__half2*)d_ws;
        hipLaunchKernelGGL(repack_kernel, dim3(NCODES / 4), dim3(256), 0, stream,
                           codes, shc, rec);
        hipLaunchKernelGGL(shcode_phased2, dim3(NBLK), dim3(256), 0, stream,
                           qp, vd, cpos, rec, knn, out);
    } else {
        hipLaunchKernelGGL(shcode_kernel, dim3(NPTS / 4), dim3(256), 0, stream,
                           qp, vd, cpos, codes, shc, knn, out);
    }
}

// Round 6
// 51.860 us; speedup vs baseline: 4.3428x; 1.4287x over previous
//
#include <hip/hip_runtime.h>

#define NPTS   65536
#define KNN    8
#define CDIM   64
#define SHB    9
#define NCODES 8192
#define NPHASE 4
#define PSHIFT 11  // 2048 codes/slice -> 2.6 MB slice fits 4 MB per-XCD L2
#define PTSW   8   // points per wave
#define WAVES  4
#define NBLK   (NPTS / (PTSW * WAVES))   // 2048 blocks -> 8 blocks/CU
#define LSTRIDE 80 // per-point LDS: ids u16[8]@0, wbar f32[8]@16, smh u32[4]@48, sm8 f32@64, mask u32@68

#if defined(__has_builtin)
#if __has_builtin(__builtin_amdgcn_fdot2)
#define HAS_FDOT2 1
#endif
#endif

typedef _Float16 half2v __attribute__((ext_vector_type(2)));

static __device__ __forceinline__ unsigned int pk16(float a, float b) {
    union { unsigned int u; _Float16 h[2]; } x;
    x.h[0] = (_Float16)a; x.h[1] = (_Float16)b;
    return x.u;
}
static __device__ __forceinline__ half2v as_h2(unsigned int u) {
    union { unsigned int u; half2v h; } x; x.u = u; return x.h;
}

// recA: (8192, 64) x 16 B  -> dwords (s0,s1)(s2,s3)(s4,s5)(s6,s7), lane-contiguous
// recB: (8192, 64) x  4 B  -> dword (s8, code)
// Per neighbor gather: ONE dwordx4 + ONE dword (was five dwords) at identical
// bytes/cachelines -> tests the per-VMEM-instruction cost model.

__global__ __launch_bounds__(256) void repack_kernel(
    const float* __restrict__ codes,   // (8192,64)
    const float* __restrict__ shc,     // (8192,576)
    unsigned int* __restrict__ recA,   // (8192*256) dwords
    unsigned int* __restrict__ recB)   // (8192*64) dwords
{
    const int wid  = threadIdx.x >> 6;
    const int lane = threadIdx.x & 63;   // dim
    const int c    = blockIdx.x * 4 + wid;

    const float* p = shc + (size_t)c * (CDIM * SHB) + lane * SHB;
    float v[SHB];
#pragma unroll
    for (int s = 0; s < SHB; ++s) v[s] = p[s];
    const float cv = codes[c * CDIM + lane];

    uint4 a;
    a.x = pk16(v[0], v[1]);
    a.y = pk16(v[2], v[3]);
    a.z = pk16(v[4], v[5]);
    a.w = pk16(v[6], v[7]);
    *reinterpret_cast<uint4*>(recA + (size_t)c * 256 + 4 * lane) = a;
    recB[(size_t)c * 64 + lane] = pk16(v[8], cv);
}

__global__ __launch_bounds__(256) void shcode_phased3(
    const float* __restrict__ qp,
    const float* __restrict__ vd,
    const float* __restrict__ cpos,
    const unsigned int* __restrict__ recA,
    const unsigned int* __restrict__ recB,
    const int*   __restrict__ knn,
    float* __restrict__ out)
{
    __shared__ unsigned char lds[WAVES * PTSW * LSTRIDE];   // 2560 B

    const int tid   = threadIdx.x;
    const int lane  = tid & 63;
    const int wid   = tid >> 6;
    const int pbase = (blockIdx.x * WAVES + wid) * PTSW;

    // ---- precompute: lane l (< PTSW) owns point pbase+l ----
    if (lane < PTSW) {
        const int n = pbase + lane;
        unsigned char* pr = lds + (wid * PTSW + lane) * LSTRIDE;
        unsigned short* ids16 = (unsigned short*)(pr + 0);
        float*          wbar  = (float*)(pr + 16);
        unsigned int*   smh   = (unsigned int*)(pr + 48);
        float*          sm8p  = (float*)(pr + 64);
        unsigned int*   maskp = (unsigned int*)(pr + 68);

        const float qx = qp[n * 3 + 0];
        const float qy = qp[n * 3 + 1];
        const float qz = qp[n * 3 + 2];

        int   ids[KNN];
        float w[KNN];
        float wsum = 0.0f;
#pragma unroll
        for (int k = 0; k < KNN; ++k) {
            const int id = knn[n * KNN + k];
            ids[k] = id;
            const float dx = qx - cpos[id * 3 + 0];
            const float dy = qy - cpos[id * 3 + 1];
            const float dz = qz - cpos[id * 3 + 2];
            w[k] = 1.0f / (dx * dx + dy * dy + dz * dz + 1e-16f);
            wsum += w[k];
        }
        const float inv = 1.0f / wsum;
        unsigned int mask = 0u;
#pragma unroll
        for (int k = 0; k < KNN; ++k) {
            ids16[k] = (unsigned short)ids[k];
            wbar[k]  = w[k] * inv;
            mask |= 1u << (((unsigned)ids[k] >> PSHIFT) * 8 + k);
        }
        *maskp = mask;

        const float x = vd[n * 3 + 0];
        const float y = vd[n * 3 + 1];
        const float z = vd[n * 3 + 2];
        const float xx = x * x, yy = y * y, zz = z * z;
        const float sm0 = 0.28209479177387814f;
        const float sm1 = -0.4886025119029199f * y;
        const float sm2 =  0.4886025119029199f * z;
        const float sm3 = -0.4886025119029199f * x;
        const float sm4 =  1.0925484305920792f * (x * y);
        const float sm5 = -1.0925484305920792f * (y * z);
        const float sm6 =  0.31539156525252005f * (2.0f * zz - xx - yy);
        const float sm7 = -1.0925484305920792f * (x * z);
        const float sm8 =  0.5462742152960396f * (xx - yy);
        smh[0] = pk16(sm0, sm1);
        smh[1] = pk16(sm2, sm3);
        smh[2] = pk16(sm4, sm5);
        smh[3] = pk16(sm6, sm7);
        *sm8p  = sm8;
    }
    __syncthreads();

    float acc_c[PTSW], acc_s[PTSW];
#pragma unroll
    for (int p = 0; p < PTSW; ++p) { acc_c[p] = 0.0f; acc_s[p] = 0.0f; }

    for (int ph = 0; ph < NPHASE; ++ph) {
#pragma unroll
        for (int p = 0; p < PTSW; ++p) {
            const unsigned char* pr = lds + (wid * PTSW + p) * LSTRIDE;
            const unsigned int mask =
                (unsigned int)__builtin_amdgcn_readfirstlane(
                    (int)*(const unsigned int*)(pr + 68));
            unsigned int m8 = (mask >> (8 * ph)) & 0xffu;
            if (!m8) continue;                      // uniform scalar branch

            const unsigned int* smu = (const unsigned int*)(pr + 48);
            const half2v smh0 = as_h2(smu[0]);
            const half2v smh1 = as_h2(smu[1]);
            const half2v smh2 = as_h2(smu[2]);
            const half2v smh3 = as_h2(smu[3]);
            const float  sm8f = *(const float*)(pr + 64);

            while (m8) {
                const int k = __builtin_ctz(m8);
                m8 &= m8 - 1u;
                const int id = __builtin_amdgcn_readfirstlane(
                    (int)((const unsigned short*)pr)[k]);
                const float wk = ((const float*)(pr + 16))[k];

                const uint4 A = *reinterpret_cast<const uint4*>(
                    recA + (size_t)id * 256 + 4 * lane);
                const unsigned int B = recB[(size_t)id * 64 + lane];

                const half2v b2 = as_h2(B);
                const float f8 = (float)b2[0];
                const float fc = (float)b2[1];

#ifdef HAS_FDOT2
                float agg = sm8f * f8;
                agg = __builtin_amdgcn_fdot2(as_h2(A.w), smh3, agg, false);
                agg = __builtin_amdgcn_fdot2(as_h2(A.z), smh2, agg, false);
                agg = __builtin_amdgcn_fdot2(as_h2(A.y), smh1, agg, false);
                agg = __builtin_amdgcn_fdot2(as_h2(A.x), smh0, agg, false);
#else
                const half2v a0 = as_h2(A.x), a1 = as_h2(A.y);
                const half2v a2 = as_h2(A.z), a3 = as_h2(A.w);
                float agg = sm8f * f8;
                agg += (float)a0[0] * (float)smh0[0] + (float)a0[1] * (float)smh0[1];
                agg += (float)a1[0] * (float)smh1[0] + (float)a1[1] * (float)smh1[1];
                agg += (float)a2[0] * (float)smh2[0] + (float)a2[1] * (float)smh2[1];
                agg += (float)a3[0] * (float)smh3[0] + (float)a3[1] * (float)smh3[1];
#endif
                acc_s[p] += wk * agg;
                acc_c[p] += wk * fc;
            }
        }
        __syncthreads();   // keep block's waves phase-aligned
    }

#pragma unroll
    for (int p = 0; p < PTSW; ++p) {
        const int n = pbase + p;
        __builtin_nontemporal_store(acc_c[p], &out[n * CDIM + lane]);
        __builtin_nontemporal_store(acc_s[p],
                                    &out[(size_t)NPTS * CDIM + n * CDIM + lane]);
    }
}

// --- fallback (round-1 fp32 direct-gather) if workspace too small ---
__global__ __launch_bounds__(256) void shcode_kernel(
    const float* __restrict__ qp, const float* __restrict__ vd,
    const float* __restrict__ cpos, const float* __restrict__ codes,
    const float* __restrict__ shc, const int* __restrict__ knn,
    float* __restrict__ out)
{
    const int wid  = threadIdx.x >> 6;
    const int lane = threadIdx.x & 63;
    const int n    = blockIdx.x * 4 + wid;

    const float x = vd[n * 3 + 0], y = vd[n * 3 + 1], z = vd[n * 3 + 2];
    const float xx = x * x, yy = y * y, zz = z * z;
    const float sm0 = 0.28209479177387814f;
    const float sm1 = -0.4886025119029199f * y;
    const float sm2 =  0.4886025119029199f * z;
    const float sm3 = -0.4886025119029199f * x;
    const float sm4 =  1.0925484305920792f * (x * y);
    const float sm5 = -1.0925484305920792f * (y * z);
    const float sm6 =  0.31539156525252005f * (2.0f * zz - xx - yy);
    const float sm7 = -1.0925484305920792f * (x * z);
    const float sm8 =  0.5462742152960396f * (xx - yy);

    const float qx = qp[n * 3 + 0], qy = qp[n * 3 + 1], qz = qp[n * 3 + 2];

    int idx[KNN]; float w[KNN]; float wsum = 0.0f;
#pragma unroll
    for (int k = 0; k < KNN; ++k) {
        int id = __builtin_amdgcn_readfirstlane(knn[n * KNN + k]);
        idx[k] = id;
        const float dx = qx - cpos[id * 3 + 0];
        const float dy = qy - cpos[id * 3 + 1];
        const float dz = qz - cpos[id * 3 + 2];
        const float sd = dx * dx + dy * dy + dz * dz + 1e-16f;
        w[k] = 1.0f / sd; wsum += w[k];
    }
    const float winv = 1.0f / wsum;

    float acc_c = 0.0f, acc_s = 0.0f;
#pragma unroll
    for (int k = 0; k < KNN; ++k) {
        const float wk = w[k] * winv;
        acc_c += wk * codes[(size_t)idx[k] * CDIM + lane];
        const float* p = shc + (size_t)idx[k] * (CDIM * SHB) + lane * SHB;
        acc_s += wk * (sm0 * p[0] + sm1 * p[1] + sm2 * p[2]
                     + sm3 * p[3] + sm4 * p[4] + sm5 * p[5]
                     + sm6 * p[6] + sm7 * p[7] + sm8 * p[8]);
    }
    out[n * CDIM + lane] = acc_c;
    out[(size_t)NPTS * CDIM + n * CDIM + lane] = acc_s;
}

extern "C" void kernel_launch(void* const* d_in, const int* in_sizes, int n_in,
                              void* d_out, int out_size, void* d_ws, size_t ws_size,
                              hipStream_t stream) {
    const float* qp    = (const float*)d_in[0];
    const float* vd    = (const float*)d_in[1];
    const float* cpos  = (const float*)d_in[2];
    const float* codes = (const float*)d_in[3];
    const float* shc   = (const float*)d_in[4];
    const int*   knn   = (const int*)d_in[6];
    float* out = (float*)d_out;

    const size_t recA_bytes = (size_t)NCODES * 256 * 4;  // 8 MB
    const size_t recB_bytes = (size_t)NCODES * 64 * 4;   // 2 MB

    if (ws_size >= recA_bytes + recB_bytes) {
        unsigned int* recA = (unsigned int*)d_ws;
        unsigned int* recB = (unsigned int*)((char*)d_ws + recA_bytes);
        hipLaunchKernelGGL(repack_kernel, dim3(NCODES / 4), dim3(256), 0, stream,
                           codes, shc, recA, recB);
        hipLaunchKernelGGL(shcode_phased3, dim3(NBLK), dim3(256), 0, stream,
                           qp, vd, cpos, recA, recB, knn, out);
    } else {
        hipLaunchKernelGGL(shcode_kernel, dim3(NPTS / 4), dim3(256), 0, stream,
                           qp, vd, cpos, codes, shc, knn, out);
    }
}